// Round 6
// baseline (229.429 us; speedup 1.0000x reference)
//
#include <hip/hip_runtime.h>

// x: (8, 160, 1024, 1) f32 ; W: (1, 7, 1, 32) f32
// y[n,h,w,c] = sum_k x[n,h,w+k-3] * W[k,c]   (SAME pad along w)
// per (n,w,c): m1 = max_h y, m2 = 2nd max, am = argmax_h
// out[n,h,w,c] = y[n,h,w,c] + (h==am ? m2 : m1)
//
// R5 resubmit (R5 hit GPUAcquisitionTimeout): MEASUREMENT ROUND.
// Kernel body is byte-identical to R3 (the fastest so far). kernel_launch
// launches it TWICE (idempotent pure function, no RMW) so that
// dur_us_new - dur_us_R3 = K, the true per-dispatch kernel time.
// Disambiguates: K~25 (already at write roofline, harness fills dominate
// dur_us) vs K~80 (shared wall to hunt).

#define WT 8           // w-positions per block
#define BLOCK 256      // 32 channels * 8 w

__global__ __launch_bounds__(BLOCK)
void pcc_kernel(const float* __restrict__ x,
                const float* __restrict__ Wf,
                float* __restrict__ out) {
    __shared__ float xs[160][WT + 6];   // 8960 B

    const int n  = blockIdx.x >> 7;     // 128 w-tiles per n (1024/8)
    const int wt = blockIdx.x & 127;
    const int w0 = wt * WT;
    const int tid = threadIdx.x;

    // ---- stage x[n, 0:160, w0-3 .. w0+WT+2] into LDS (zero-padded) ----
    const float* xn = x + (size_t)n * 160 * 1024;
    for (int idx = tid; idx < 160 * (WT + 6); idx += BLOCK) {
        int row = idx / (WT + 6);
        int col = idx - row * (WT + 6);
        int gw  = w0 - 3 + col;
        float v = 0.f;
        if (gw >= 0 && gw < 1024) v = xn[row * 1024 + gw];
        xs[row][col] = v;
    }
    __syncthreads();

    const int c  = tid & 31;            // channel 0..31
    const int wl = tid >> 5;            // local w 0..7

    float wg[7];
#pragma unroll
    for (int k = 0; k < 7; ++k) wg[k] = Wf[k * 32 + c];

    // ---- pass 1: top-2 + argmax over h ----
    float m1 = -INFINITY, m2 = -INFINITY;
    int am = 0;

#pragma unroll 4
    for (int h = 0; h < 160; ++h) {
        float y = 0.f;
#pragma unroll
        for (int j = 0; j < 7; ++j) y = fmaf(xs[h][wl + j], wg[j], y);
        bool g = y > m1;
        m2 = g ? m1 : fmaxf(m2, y);
        m1 = g ? y  : m1;
        am = g ? h  : am;
    }

    // ---- pass 2: recompute conv, add max-other, store ----
    float* obase = out + ((size_t)(n * 160) * 1024 + (w0 + wl)) * 32 + c;
#pragma unroll 4
    for (int h = 0; h < 160; ++h) {
        float y = 0.f;
#pragma unroll
        for (int j = 0; j < 7; ++j) y = fmaf(xs[h][wl + j], wg[j], y);
        obase[(size_t)h * 1024 * 32] = y + (h == am ? m2 : m1);
    }
}

extern "C" void kernel_launch(void* const* d_in, const int* in_sizes, int n_in,
                              void* d_out, int out_size, void* d_ws, size_t ws_size,
                              hipStream_t stream) {
    const float* x  = (const float*)d_in[0];   // 8*160*1024
    const float* Wf = (const float*)d_in[1];   // 7*32
    float* out = (float*)d_out;                // 8*160*1024*32
    dim3 grid(8 * (1024 / WT));                // 1024 blocks
    dim3 block(BLOCK);
    // Launch TWICE: second dispatch recomputes identical values (pure
    // function of d_in, no read-modify-write). dur_us delta vs R3 == one
    // kernel's true duration.
    pcc_kernel<<<grid, block, 0, stream>>>(x, Wf, out);
    pcc_kernel<<<grid, block, 0, stream>>>(x, Wf, out);
}

// Round 10
// 192.306 us; speedup vs baseline: 1.1930x; 1.1930x over previous
//
#include <hip/hip_runtime.h>

// x: (8, 160, 1024, 1) f32 ; W: (1, 7, 1, 32) f32
// y[n,h,w,c] = sum_k x[n,h,w+k-3] * W[k,c]   (SAME pad along w)
// per (n,w,c): m1 = max_h y, m2 = 2nd max, am = argmax_h
// out[n,h,w,c] = y[n,h,w,c] + (h==am ? m2 : m1)
//
// R7 resubmit x3 (infra failures): K measured at 44.2 us (R6
// double-launch); harness overhead F~141 us. Write floor ~25 us.
// Attack pass1+LDS: 2 w/thread, 4x ds_read_b64 per h serves 2 outputs
// (vs 7 b32 per output in R3), 14 FMA / 2 outputs. WT=16, 512 blocks
// x 256 thr = 8 waves/CU (R2 showed sufficient).

#define BLOCK 256
#define WT    16
#define LDSW  24     // 22 cols used (WT+6), stride 24 floats = 96 B (8B-aligned rows)

__global__ __launch_bounds__(BLOCK)
void pcc_kernel(const float* __restrict__ x,
                const float* __restrict__ Wf,
                float* __restrict__ out) {
    __shared__ __align__(16) float xs[160][LDSW];   // 15.36 KB

    const int n  = blockIdx.x >> 6;      // 64 w-tiles per n (1024/16)
    const int wt = blockIdx.x & 63;
    const int w0 = wt * WT;
    const int tid = threadIdx.x;

    // ---- stage x[n, 0:160, w0-3 .. w0+20] into LDS (zero-padded) ----
    // col j <-> global w = w0 - 3 + j
    const float* xn = x + (size_t)n * 160 * 1024;
    for (int idx = tid; idx < 160 * LDSW; idx += BLOCK) {
        int row = idx / LDSW;
        int col = idx - row * LDSW;
        int gw  = w0 - 3 + col;
        float v = 0.f;
        if (gw >= 0 && gw < 1024) v = xn[row * 1024 + gw];
        xs[row][col] = v;
    }
    __syncthreads();

    const int c = tid & 31;              // channel 0..31
    const int t = tid >> 5;              // 0..7 -> w = w0 + 2t, 2t+1

    float wg[7];
#pragma unroll
    for (int k = 0; k < 7; ++k) wg[k] = Wf[k * 32 + c];

    // taps for wA=w0+2t: cols 2t..2t+6 ; wB=+1: cols 2t+1..2t+7
    // read cols [2t, 2t+8) as 4x float2 (8B-aligned: row stride 96 B, off 8t)

    float m1a = -INFINITY, m2a = -INFINITY;
    float m1b = -INFINITY, m2b = -INFINITY;
    int ama = 0, amb = 0;

    // ---- pass 1: top-2 + argmax over h ----
#pragma unroll 4
    for (int h = 0; h < 160; ++h) {
        const float2* row = reinterpret_cast<const float2*>(&xs[h][2 * t]);
        float2 d0 = row[0], d1 = row[1], d2 = row[2], d3 = row[3];
        float f0 = d0.x, f1 = d0.y, f2 = d1.x, f3 = d1.y;
        float f4 = d2.x, f5 = d2.y, f6 = d3.x, f7 = d3.y;
        float ya = 0.f, yb = 0.f;
        ya = fmaf(f0, wg[0], ya); yb = fmaf(f1, wg[0], yb);
        ya = fmaf(f1, wg[1], ya); yb = fmaf(f2, wg[1], yb);
        ya = fmaf(f2, wg[2], ya); yb = fmaf(f3, wg[2], yb);
        ya = fmaf(f3, wg[3], ya); yb = fmaf(f4, wg[3], yb);
        ya = fmaf(f4, wg[4], ya); yb = fmaf(f5, wg[4], yb);
        ya = fmaf(f5, wg[5], ya); yb = fmaf(f6, wg[5], yb);
        ya = fmaf(f6, wg[6], ya); yb = fmaf(f7, wg[6], yb);
        bool ga = ya > m1a;
        m2a = ga ? m1a : fmaxf(m2a, ya);
        m1a = ga ? ya  : m1a;
        ama = ga ? h   : ama;
        bool gb = yb > m1b;
        m2b = gb ? m1b : fmaxf(m2b, yb);
        m1b = gb ? yb  : m1b;
        amb = gb ? h   : amb;
    }

    // ---- pass 2: recompute conv, add max-other, store 2 dwords ----
    float* obase = out + ((size_t)(n * 160) * 1024 + (w0 + 2 * t)) * 32 + c;
#pragma unroll 2
    for (int h = 0; h < 160; ++h) {
        const float2* row = reinterpret_cast<const float2*>(&xs[h][2 * t]);
        float2 d0 = row[0], d1 = row[1], d2 = row[2], d3 = row[3];
        float f0 = d0.x, f1 = d0.y, f2 = d1.x, f3 = d1.y;
        float f4 = d2.x, f5 = d2.y, f6 = d3.x, f7 = d3.y;
        float ya = 0.f, yb = 0.f;
        ya = fmaf(f0, wg[0], ya); yb = fmaf(f1, wg[0], yb);
        ya = fmaf(f1, wg[1], ya); yb = fmaf(f2, wg[1], yb);
        ya = fmaf(f2, wg[2], ya); yb = fmaf(f3, wg[2], yb);
        ya = fmaf(f3, wg[3], ya); yb = fmaf(f4, wg[3], yb);
        ya = fmaf(f4, wg[4], ya); yb = fmaf(f5, wg[4], yb);
        ya = fmaf(f5, wg[5], ya); yb = fmaf(f6, wg[5], yb);
        ya = fmaf(f6, wg[6], ya); yb = fmaf(f7, wg[6], yb);
        float* orow = obase + (size_t)h * 1024 * 32;
        orow[0]  = ya + (h == ama ? m2a : m1a);
        orow[32] = yb + (h == amb ? m2b : m1b);
    }
}

extern "C" void kernel_launch(void* const* d_in, const int* in_sizes, int n_in,
                              void* d_out, int out_size, void* d_ws, size_t ws_size,
                              hipStream_t stream) {
    const float* x  = (const float*)d_in[0];   // 8*160*1024
    const float* Wf = (const float*)d_in[1];   // 7*32
    float* out = (float*)d_out;                // 8*160*1024*32
    dim3 grid(8 * (1024 / WT));                // 512 blocks
    dim3 block(BLOCK);
    pcc_kernel<<<grid, block, 0, stream>>>(x, Wf, out);
}